// Round 3
// baseline (1079.275 us; speedup 1.0000x reference)
//
#include <hip/hip_runtime.h>

#define NN 100000
#define EE 1600000
#define DIN 512
#define DH 256
#define DOUT 32

typedef _Float16 h16x8 __attribute__((ext_vector_type(8)));
typedef _Float16 h16x4 __attribute__((ext_vector_type(4)));
typedef float f32x4 __attribute__((ext_vector_type(4)));

union HU2 { uint2 u; _Float16 h[4]; };

__device__ __forceinline__ void gload16(const void* g, void* l){
  __builtin_amdgcn_global_load_lds((const __attribute__((address_space(1))) void*)g,
                                   (__attribute__((address_space(3))) void*)l, 16, 0, 0);
}

// ---------- weight transpose + fp16 convert ----------
__global__ __launch_bounds__(256) void conv_w1(const float* __restrict__ W1, _Float16* __restrict__ W1T){
  int i = blockIdx.x*256 + threadIdx.x;
  if (i < DIN*DH){
    int c = i >> 9, k = i & 511;          // W1T[c][k] = W1[k][c]
    W1T[i] = (_Float16)W1[k*DH + c];
  }
}
__global__ __launch_bounds__(256) void conv_w2(const float* __restrict__ W2, _Float16* __restrict__ W2T){
  int i = blockIdx.x*256 + threadIdx.x;
  if (i < DH*DOUT){
    int c = i >> 8, k = i & 255;          // W2T[c][k] = W2[k][c]
    W2T[i] = (_Float16)W2[k*DOUT + c];
  }
}

// ---------- GEMM1: h1 = feats @ W1 + b1 ----------
// A: global_load_lds (fp32 raw, XOR-swizzled via pre-swizzled global src, linear LDS dest)
// B: reg-staged into pad-40 LDS. fp32->fp16 convert at fragment read. 2-barrier dbuf.
__global__ __launch_bounds__(256) void gemm1(const float* __restrict__ feats,
    const _Float16* __restrict__ W1T, const float* __restrict__ b1,
    float* __restrict__ h1)
{
  __shared__ float Af[2][128*32];        // [row][physslot*4] fp32, 16KB each
  __shared__ _Float16 Bt[2][128][40];    // pad 40 (80B stride, 2-way = free)
  const int tid = threadIdx.x;
  const int row0 = blockIdx.x * 128;
  const int col0 = blockIdx.y * 128;
  const int lane = tid & 63;
  const int wave = tid >> 6;
  const int wr = wave >> 1, wc = wave & 1;
  const int l15 = lane & 15, kg = lane >> 4;
  // A staging: issue q covers rows wave*32+q*8 .. +8; lane -> (row=+lane>>3, phys slot=lane&7)
  const int lrow = lane >> 3;
  const int klog = (lane & 7) ^ lrow;     // logical k-slot this lane must fetch (involution)
  // B staging
  const int sRow = tid >> 1;
  const int sHalf = (tid & 1) * 16;
  const _Float16* bP = W1T + (size_t)(col0 + sRow)*DIN + sHalf;

  f32x4 acc[4][4];
#pragma unroll
  for (int m=0;m<4;m++)
#pragma unroll
    for (int n=0;n<4;n++){ acc[m][n][0]=0.f; acc[m][n][1]=0.f; acc[m][n][2]=0.f; acc[m][n][3]=0.f; }

  auto issueA = [&](int buf, int k0){
#pragma unroll
    for (int q=0;q<4;q++){
      int rl = wave*32 + q*8;
      if (row0 + rl < NN){   // NN%8==0 -> whole-issue guard exact
        const float* g = feats + (size_t)(row0 + rl + lrow)*DIN + k0 + klog*4;
        gload16(g, &Af[buf][rl*32]);
      }
    }
  };

  h16x8 bv0, bv1;
  issueA(0, 0);
  bv0 = *reinterpret_cast<const h16x8*>(bP);
  bv1 = *reinterpret_cast<const h16x8*>(bP + 8);

  const int s0 = (2*kg) ^ (l15 & 7);      // phys slot of logical slot 2kg (row&7 == l15&7)

  for (int t=0; t<16; ++t){
    const int c = t & 1;
    *reinterpret_cast<h16x8*>(&Bt[c][sRow][sHalf])   = bv0;
    *reinterpret_cast<h16x8*>(&Bt[c][sRow][sHalf+8]) = bv1;
    __syncthreads();                       // publishes Af[c] (vmcnt drain) + Bt[c]
    if (t < 15){
      issueA(c^1, (t+1)*32);               // next tile in flight under this tile's compute
      bv0 = *reinterpret_cast<const h16x8*>(bP + (t+1)*32);
      bv1 = *reinterpret_cast<const h16x8*>(bP + (t+1)*32 + 8);
    }
    h16x8 af[4], bfr[4];
#pragma unroll
    for (int m=0;m<4;m++){
      const int row = wr*64 + m*16 + l15;
      const float* rp = &Af[c][row*32];
      float4 x = *reinterpret_cast<const float4*>(rp + s0*4);        // logical k: kg*8..+4
      float4 y = *reinterpret_cast<const float4*>(rp + (s0^1)*4);    // logical k: kg*8+4..+8
      h16x8 v;
      v[0]=(_Float16)x.x; v[1]=(_Float16)x.y; v[2]=(_Float16)x.z; v[3]=(_Float16)x.w;
      v[4]=(_Float16)y.x; v[5]=(_Float16)y.y; v[6]=(_Float16)y.z; v[7]=(_Float16)y.w;
      af[m] = v;
    }
#pragma unroll
    for (int n=0;n<4;n++) bfr[n] = *reinterpret_cast<const h16x8*>(&Bt[c][wc*64 + n*16 + l15][kg*8]);
#pragma unroll
    for (int m=0;m<4;m++)
#pragma unroll
      for (int n=0;n<4;n++)
        acc[m][n] = __builtin_amdgcn_mfma_f32_16x16x32_f16(af[m], bfr[n], acc[m][n], 0, 0, 0);
    __syncthreads();
  }
  const int rb = kg*4;
#pragma unroll
  for (int n=0;n<4;n++){
    int col = col0 + wc*64 + n*16 + l15;
    float bias = b1[col];
#pragma unroll
    for (int m=0;m<4;m++){
#pragma unroll
      for (int j=0;j<4;j++){
        int g = row0 + wr*64 + m*16 + rb + j;
        if (g < NN) h1[(size_t)g*DH + col] = acc[m][n][j] + bias;
      }
    }
  }
}

// ---------- GEMM2: h0 = relu(h1) @ W2 + b2 -> half-split fp16 (plain + nS-scaled) ----------
__global__ __launch_bounds__(256) void gemm2(const float* __restrict__ h1,
    const _Float16* __restrict__ W2T, const float* __restrict__ b2,
    const float* __restrict__ nS,
    _Float16* __restrict__ h0a, _Float16* __restrict__ h0b,
    _Float16* __restrict__ hs0a, _Float16* __restrict__ hs0b)
{
  __shared__ _Float16 At[256][40];
  __shared__ _Float16 Bt[32][264];
  const int tid = threadIdx.x;
  const int row0 = blockIdx.x * 256;
  {
    int r = tid >> 3, c0 = (tid & 7) * 32;
    const h16x8* s = reinterpret_cast<const h16x8*>(W2T + r*DH + c0);
    h16x8* d = reinterpret_cast<h16x8*>(&Bt[r][c0]);
#pragma unroll
    for (int j=0;j<4;j++) d[j] = s[j];
  }
  const int lane = tid & 63, wave = tid >> 6;
  const int l15 = lane & 15, kg = lane >> 4;
  f32x4 acc[4][2];
#pragma unroll
  for (int m=0;m<4;m++)
#pragma unroll
    for (int n=0;n<2;n++){ acc[m][n][0]=0.f; acc[m][n][1]=0.f; acc[m][n][2]=0.f; acc[m][n][3]=0.f; }
  const int g = row0 + tid;
  const bool aok = (g < NN);

  float4 f[8];
#pragma unroll
  for (int j=0;j<8;j++) f[j]=make_float4(0.f,0.f,0.f,0.f);
  if (aok){
    const float4* p = reinterpret_cast<const float4*>(h1 + (size_t)g*DH);
#pragma unroll
    for (int j=0;j<8;j++) f[j]=p[j];
  }

  for (int k0=0;k0<DH;k0+=32){
#pragma unroll
    for (int j=0;j<8;j++){
      h16x4 v;
      v[0]=(_Float16)fmaxf(f[j].x,0.f); v[1]=(_Float16)fmaxf(f[j].y,0.f);
      v[2]=(_Float16)fmaxf(f[j].z,0.f); v[3]=(_Float16)fmaxf(f[j].w,0.f);
      *reinterpret_cast<h16x4*>(&At[tid][j*4]) = v;
    }
    __syncthreads();
    if (aok && k0 + 32 < DH){
      const float4* p = reinterpret_cast<const float4*>(h1 + (size_t)g*DH + k0 + 32);
#pragma unroll
      for (int j=0;j<8;j++) f[j]=p[j];
    }
    h16x8 af[4], bfr[2];
#pragma unroll
    for (int m=0;m<4;m++) af[m]  = *reinterpret_cast<const h16x8*>(&At[wave*64 + m*16 + l15][kg*8]);
#pragma unroll
    for (int n=0;n<2;n++) bfr[n] = *reinterpret_cast<const h16x8*>(&Bt[n*16 + l15][k0 + kg*8]);
#pragma unroll
    for (int m=0;m<4;m++)
#pragma unroll
      for (int n=0;n<2;n++)
        acc[m][n] = __builtin_amdgcn_mfma_f32_16x16x32_f16(af[m], bfr[n], acc[m][n], 0,0,0);
    __syncthreads();
  }
  const int rb = kg*4;
#pragma unroll
  for (int n=0;n<2;n++){
    int col = n*16 + l15;               // n==0 -> half a, n==1 -> half b
    float bias = b2[col];
#pragma unroll
    for (int m=0;m<4;m++){
#pragma unroll
      for (int j=0;j<4;j++){
        int gr = row0 + wave*64 + m*16 + rb + j;
        if (gr < NN){
          float val = acc[m][n][j] + bias;
          float sv  = nS[gr] * val;
          if (n == 0){
            h0a [(size_t)gr*16 + l15] = (_Float16)val;
            hs0a[(size_t)gr*16 + l15] = (_Float16)sv;
          } else {
            h0b [(size_t)gr*16 + l15] = (_Float16)val;
            hs0b[(size_t)gr*16 + l15] = (_Float16)sv;
          }
        }
      }
    }
  }
}

// ---------- graph prep ----------
__global__ __launch_bounds__(256) void deg_kernel(const int* __restrict__ src, const int* __restrict__ dst,
    int* __restrict__ degO, int* __restrict__ degI){
  int i = blockIdx.x*256 + threadIdx.x;
  if (i < EE){
    atomicAdd(&degO[src[i]], 1);
    atomicAdd(&degI[dst[i]], 1);
  }
}
__global__ __launch_bounds__(256) void norm_kernel(const int* __restrict__ degO, const int* __restrict__ degI,
    float* __restrict__ nS, float* __restrict__ nD){
  int i = blockIdx.x*256 + threadIdx.x;
  if (i < NN){
    int a = degO[i] > 0 ? degO[i] : 1;
    int b = degI[i] > 0 ? degI[i] : 1;
    nS[i] = 1.0f/sqrtf((float)a);
    nD[i] = 1.0f/sqrtf((float)b);
  }
}
__global__ __launch_bounds__(1024) void scan1(const int* __restrict__ degI, int* __restrict__ offs, int* __restrict__ bsum){
  __shared__ int sm[1024];
  int t = threadIdx.x;
  int g = blockIdx.x*1024 + t;
  int v = (g < NN) ? degI[g] : 0;
  sm[t] = v; __syncthreads();
  for (int o=1;o<1024;o<<=1){
    int a = (t>=o)? sm[t-o] : 0;
    __syncthreads();
    sm[t] += a;
    __syncthreads();
  }
  if (g < NN) offs[g] = sm[t] - v;
  if (t == 1023) bsum[blockIdx.x] = sm[t];
}
__global__ __launch_bounds__(128) void scan2(const int* __restrict__ bsum, int* __restrict__ boff, int nb){
  __shared__ int sm[128];
  int t = threadIdx.x;
  int v = (t < nb)? bsum[t] : 0;
  sm[t] = v; __syncthreads();
  for (int o=1;o<128;o<<=1){
    int a = (t>=o)? sm[t-o] : 0;
    __syncthreads();
    sm[t] += a;
    __syncthreads();
  }
  if (t < nb) boff[t] = sm[t] - v;
}
__global__ __launch_bounds__(256) void scan3(int* __restrict__ offs, const int* __restrict__ boff){
  int i = blockIdx.x*256 + threadIdx.x;
  if (i < NN) offs[i] += boff[i >> 10];
}
__global__ __launch_bounds__(256) void scatter_kernel(const int* __restrict__ src, const int* __restrict__ dst,
    const int* __restrict__ offs, int* __restrict__ cursor,
    int* __restrict__ csrc){
  int i = blockIdx.x*256 + threadIdx.x;
  if (i < EE){
    int d = dst[i], s = src[i];
    int pos = offs[d] + atomicAdd(&cursor[d], 1);
    csrc[pos] = s;
  }
}

// ---------- APPNP pull propagation, one 16-feature half (L2-resident gather set) ----------
template<bool LAST>
__global__ __launch_bounds__(256) void prop_half(
    const uint2* __restrict__ hs,      // scaled fp16 half rows [NN][4]
    const uint2* __restrict__ h0,      // unscaled fp16 half rows [NN][4]
    uint2* __restrict__ hs_out,        // next scaled (if !LAST)
    float* __restrict__ outf,          // f32 out base, pre-offset by half*16 (if LAST)
    const int* __restrict__ offs, const int* __restrict__ degI,
    const int* __restrict__ csrc,
    const float* __restrict__ nS, const float* __restrict__ nD)
{
  int v = blockIdx.x*4 + (threadIdx.x >> 6);
  if (v >= NN) return;
  int lane = threadIdx.x & 63;
  int slot = lane >> 2, c = lane & 3;   // 16 edge slots x 4 feature-quads
  int beg = offs[v], cnt = degI[v];
  float a0=0.f, a1=0.f, a2=0.f, a3=0.f;
  for (int i = slot; i < cnt; i += 16){
    int s = csrc[beg + i];
    HU2 p; p.u = hs[(size_t)s*4 + c];
    a0 += (float)p.h[0]; a1 += (float)p.h[1];
    a2 += (float)p.h[2]; a3 += (float)p.h[3];
  }
  a0 += __shfl_xor(a0,4);  a1 += __shfl_xor(a1,4);  a2 += __shfl_xor(a2,4);  a3 += __shfl_xor(a3,4);
  a0 += __shfl_xor(a0,8);  a1 += __shfl_xor(a1,8);  a2 += __shfl_xor(a2,8);  a3 += __shfl_xor(a3,8);
  a0 += __shfl_xor(a0,16); a1 += __shfl_xor(a1,16); a2 += __shfl_xor(a2,16); a3 += __shfl_xor(a3,16);
  a0 += __shfl_xor(a0,32); a1 += __shfl_xor(a1,32); a2 += __shfl_xor(a2,32); a3 += __shfl_xor(a3,32);
  if (slot == 0){
    float nd = nD[v];
    HU2 hp; hp.u = h0[(size_t)v*4 + c];
    float r0 = 0.9f*nd*a0 + 0.1f*(float)hp.h[0];
    float r1 = 0.9f*nd*a1 + 0.1f*(float)hp.h[1];
    float r2 = 0.9f*nd*a2 + 0.1f*(float)hp.h[2];
    float r3 = 0.9f*nd*a3 + 0.1f*(float)hp.h[3];
    if (LAST){
      *reinterpret_cast<float4*>(&outf[(size_t)v*32 + c*4]) = make_float4(r0,r1,r2,r3);
    } else {
      float ns = nS[v];
      HU2 o;
      o.h[0]=(_Float16)(ns*r0); o.h[1]=(_Float16)(ns*r1);
      o.h[2]=(_Float16)(ns*r2); o.h[3]=(_Float16)(ns*r3);
      hs_out[(size_t)v*4 + c] = o.u;
    }
  }
}

extern "C" void kernel_launch(void* const* d_in, const int* in_sizes, int n_in,
                              void* d_out, int out_size, void* d_ws, size_t ws_size,
                              hipStream_t stream)
{
  const float* feats = (const float*)d_in[0];
  const int*   src   = (const int*)d_in[1];
  const int*   dst   = (const int*)d_in[2];
  const float* W1    = (const float*)d_in[3];
  const float* b1    = (const float*)d_in[4];
  const float* W2    = (const float*)d_in[5];
  const float* b2    = (const float*)d_in[6];
  float* out = (float*)d_out;

  char* ws = (char*)d_ws;
  size_t off = 0;
  auto alloc = [&](size_t bytes) -> void* {
    void* p = ws + off;
    off = (off + bytes + 255) & ~(size_t)255;
    return p;
  };
  _Float16* W1T = (_Float16*)alloc((size_t)DIN*DH*2);
  _Float16* W2T = (_Float16*)alloc((size_t)DH*DOUT*2);
  int*   degO   = (int*)  alloc((size_t)NN*4);
  int*   degI   = (int*)  alloc((size_t)NN*4);
  float* nS     = (float*)alloc((size_t)NN*4);
  float* nD     = (float*)alloc((size_t)NN*4);
  int*   offs   = (int*)  alloc((size_t)NN*4);
  int*   cursor = (int*)  alloc((size_t)NN*4);
  int*   bsum   = (int*)  alloc(512);
  int*   boff   = (int*)  alloc(512);
  int*   csrc   = (int*)  alloc((size_t)EE*4);
  _Float16* h0a  = (_Float16*)alloc((size_t)NN*16*2);
  _Float16* h0b  = (_Float16*)alloc((size_t)NN*16*2);
  _Float16* hs0a = (_Float16*)alloc((size_t)NN*16*2);
  _Float16* hs0b = (_Float16*)alloc((size_t)NN*16*2);
  uint2* pA = (uint2*)alloc((size_t)NN*16*2);
  uint2* pB = (uint2*)alloc((size_t)NN*16*2);

  hipMemsetAsync(degO,   0, (size_t)NN*4, stream);
  hipMemsetAsync(degI,   0, (size_t)NN*4, stream);
  hipMemsetAsync(cursor, 0, (size_t)NN*4, stream);

  conv_w1<<<(DIN*DH+255)/256, 256, 0, stream>>>(W1, W1T);
  conv_w2<<<(DH*DOUT+255)/256, 256, 0, stream>>>(W2, W2T);

  deg_kernel<<<(EE+255)/256, 256, 0, stream>>>(src, dst, degO, degI);
  norm_kernel<<<(NN+255)/256, 256, 0, stream>>>(degO, degI, nS, nD);

  gemm1<<<dim3((NN+127)/128, DH/128), 256, 0, stream>>>(feats, W1T, b1, out);
  gemm2<<<(NN+255)/256, 256, 0, stream>>>(out, W2T, b2, nS, h0a, h0b, hs0a, hs0b);

  int nb = (NN+1023)/1024;
  scan1<<<nb, 1024, 0, stream>>>(degI, offs, bsum);
  scan2<<<1, 128, 0, stream>>>(bsum, boff, nb);
  scan3<<<(NN+255)/256, 256, 0, stream>>>(offs, boff);
  scatter_kernel<<<(EE+255)/256, 256, 0, stream>>>(src, dst, offs, cursor, csrc);

  float* outh_f = out + (size_t)NN*DH;
  int nbv = (NN + 3) / 4;
  for (int half = 0; half < 2; ++half){
    const uint2* h0h = (const uint2*)(half ? h0b : h0a);
    const uint2* cur = (const uint2*)(half ? hs0b : hs0a);
    float* ob = outh_f + half*16;
    for (int it=0; it<9; ++it){
      uint2* nxt = (it&1)? pB : pA;
      prop_half<false><<<nbv, 256, 0, stream>>>(cur, h0h, nxt, nullptr, offs, degI, csrc, nS, nD);
      cur = nxt;
    }
    prop_half<true><<<nbv, 256, 0, stream>>>(cur, h0h, nullptr, ob, offs, degI, csrc, nS, nD);
  }
}

// Round 4
// 783.042 us; speedup vs baseline: 1.3783x; 1.3783x over previous
//
#include <hip/hip_runtime.h>

#define NN 100000
#define EE 1600000
#define DIN 512
#define DH 256
#define DOUT 32

typedef _Float16 h16x8 __attribute__((ext_vector_type(8)));
typedef _Float16 h16x4 __attribute__((ext_vector_type(4)));
typedef float f32x4 __attribute__((ext_vector_type(4)));

union HU { unsigned int u; _Float16 h[2]; };

// ---------- weight transpose + fp16 convert ----------
__global__ __launch_bounds__(256) void conv_w1(const float* __restrict__ W1, _Float16* __restrict__ W1T){
  int i = blockIdx.x*256 + threadIdx.x;
  if (i < DIN*DH){
    int c = i >> 9, k = i & 511;          // W1T[c][k] = W1[k][c]
    W1T[i] = (_Float16)W1[k*DH + c];
  }
}
__global__ __launch_bounds__(256) void conv_w2(const float* __restrict__ W2, _Float16* __restrict__ W2T){
  int i = blockIdx.x*256 + threadIdx.x;
  if (i < DH*DOUT){
    int c = i >> 8, k = i & 255;          // W2T[c][k] = W2[k][c]
    W2T[i] = (_Float16)W2[k*DOUT + c];
  }
}

// ---------- GEMM1: h1 = feats @ W1 + b1  (BM=64 x BN=128, occupancy-first) ----------
__global__ __launch_bounds__(256) void gemm1(const float* __restrict__ feats,
    const _Float16* __restrict__ W1T, const float* __restrict__ b1,
    float* __restrict__ h1)
{
  __shared__ _Float16 At[64][40];
  __shared__ _Float16 Bt[128][40];
  const int tid = threadIdx.x;
  const int col0 = blockIdx.x * 128;
  const int row0 = blockIdx.y * 64;
  const int lane = tid & 63, wave = tid >> 6;
  const int wr = wave >> 1, wc = wave & 1;
  const int l15 = lane & 15, kg = lane >> 4;
  const int arow = tid >> 2, aseg = (tid & 3) * 8;   // A: 64 rows x 32 k, 8 floats/thread
  const int bcol = tid >> 1, bseg = (tid & 1) * 16;  // B: 128 cols x 32 k, 16 halfs/thread
  const bool aok = (row0 + arow) < NN;
  const float* aP = feats + (size_t)(row0+arow)*DIN + aseg;
  const _Float16* bP = W1T + (size_t)(col0+bcol)*DIN + bseg;

  f32x4 acc[2][4];
#pragma unroll
  for (int m=0;m<2;m++)
#pragma unroll
    for (int n=0;n<4;n++){ acc[m][n][0]=0.f; acc[m][n][1]=0.f; acc[m][n][2]=0.f; acc[m][n][3]=0.f; }

  float4 fa0 = make_float4(0,0,0,0), fa1 = make_float4(0,0,0,0);
  h16x8 fb0, fb1;
  if (aok){
    fa0 = *reinterpret_cast<const float4*>(aP);
    fa1 = *reinterpret_cast<const float4*>(aP + 4);
  }
  fb0 = *reinterpret_cast<const h16x8*>(bP);
  fb1 = *reinterpret_cast<const h16x8*>(bP + 8);

  for (int t=0; t<16; ++t){
    {
      h16x4 v0, v1;
      v0[0]=(_Float16)fa0.x; v0[1]=(_Float16)fa0.y; v0[2]=(_Float16)fa0.z; v0[3]=(_Float16)fa0.w;
      v1[0]=(_Float16)fa1.x; v1[1]=(_Float16)fa1.y; v1[2]=(_Float16)fa1.z; v1[3]=(_Float16)fa1.w;
      *reinterpret_cast<h16x4*>(&At[arow][aseg])   = v0;
      *reinterpret_cast<h16x4*>(&At[arow][aseg+4]) = v1;
      *reinterpret_cast<h16x8*>(&Bt[bcol][bseg])   = fb0;
      *reinterpret_cast<h16x8*>(&Bt[bcol][bseg+8]) = fb1;
    }
    __syncthreads();
    if (t < 15){
      int k0 = (t+1)*32;
      if (aok){
        fa0 = *reinterpret_cast<const float4*>(aP + k0);
        fa1 = *reinterpret_cast<const float4*>(aP + k0 + 4);
      }
      fb0 = *reinterpret_cast<const h16x8*>(bP + k0);
      fb1 = *reinterpret_cast<const h16x8*>(bP + k0 + 8);
    }
    h16x8 af[2], bfr[4];
#pragma unroll
    for (int m=0;m<2;m++) af[m]  = *reinterpret_cast<const h16x8*>(&At[wr*32 + m*16 + l15][kg*8]);
#pragma unroll
    for (int n=0;n<4;n++) bfr[n] = *reinterpret_cast<const h16x8*>(&Bt[wc*64 + n*16 + l15][kg*8]);
#pragma unroll
    for (int m=0;m<2;m++)
#pragma unroll
      for (int n=0;n<4;n++)
        acc[m][n] = __builtin_amdgcn_mfma_f32_16x16x32_f16(af[m], bfr[n], acc[m][n], 0, 0, 0);
    __syncthreads();
  }
  const int rb = kg*4;
#pragma unroll
  for (int n=0;n<4;n++){
    int col = col0 + wc*64 + n*16 + l15;
    float bias = b1[col];
#pragma unroll
    for (int m=0;m<2;m++){
#pragma unroll
      for (int j=0;j<4;j++){
        int g = row0 + wr*32 + m*16 + rb + j;
        if (g < NN) h1[(size_t)g*DH + col] = acc[m][n][j] + bias;
      }
    }
  }
}

// ---------- GEMM2: h0 = relu(h1) @ W2 + b2 -> full-row fp16 (plain + nS-scaled) ----------
__global__ __launch_bounds__(256) void gemm2(const float* __restrict__ h1,
    const _Float16* __restrict__ W2T, const float* __restrict__ b2,
    const float* __restrict__ nS,
    _Float16* __restrict__ h0h, _Float16* __restrict__ hsh)
{
  __shared__ _Float16 At[64][40];
  __shared__ _Float16 Bt[32][264];
  const int tid = threadIdx.x;
  const int row0 = blockIdx.x * 64;
  {
    int r = tid >> 3, c0 = (tid & 7) * 32;
    const h16x8* s = reinterpret_cast<const h16x8*>(W2T + r*DH + c0);
    h16x8* d = reinterpret_cast<h16x8*>(&Bt[r][c0]);
#pragma unroll
    for (int j=0;j<4;j++) d[j] = s[j];
  }
  const int lane = tid & 63, wave = tid >> 6;
  const int l15 = lane & 15, kg = lane >> 4;
  const int arow = tid >> 2, aseg = (tid & 3) * 8;
  const bool aok = (row0 + arow) < NN;
  const float* aP = h1 + (size_t)(row0+arow)*DH + aseg;

  f32x4 acc[2];
#pragma unroll
  for (int n=0;n<2;n++){ acc[n][0]=0.f; acc[n][1]=0.f; acc[n][2]=0.f; acc[n][3]=0.f; }

  float4 fa0 = make_float4(0,0,0,0), fa1 = make_float4(0,0,0,0);
  if (aok){
    fa0 = *reinterpret_cast<const float4*>(aP);
    fa1 = *reinterpret_cast<const float4*>(aP + 4);
  }
  for (int t=0; t<8; ++t){
    {
      h16x4 v0, v1;
      v0[0]=(_Float16)fmaxf(fa0.x,0.f); v0[1]=(_Float16)fmaxf(fa0.y,0.f);
      v0[2]=(_Float16)fmaxf(fa0.z,0.f); v0[3]=(_Float16)fmaxf(fa0.w,0.f);
      v1[0]=(_Float16)fmaxf(fa1.x,0.f); v1[1]=(_Float16)fmaxf(fa1.y,0.f);
      v1[2]=(_Float16)fmaxf(fa1.z,0.f); v1[3]=(_Float16)fmaxf(fa1.w,0.f);
      *reinterpret_cast<h16x4*>(&At[arow][aseg])   = v0;
      *reinterpret_cast<h16x4*>(&At[arow][aseg+4]) = v1;
    }
    __syncthreads();
    if (t < 7){
      int k0 = (t+1)*32;
      if (aok){
        fa0 = *reinterpret_cast<const float4*>(aP + k0);
        fa1 = *reinterpret_cast<const float4*>(aP + k0 + 4);
      }
    }
    h16x8 af, bfr[2];
    af = *reinterpret_cast<const h16x8*>(&At[wave*16 + l15][kg*8]);
#pragma unroll
    for (int n=0;n<2;n++) bfr[n] = *reinterpret_cast<const h16x8*>(&Bt[n*16 + l15][t*32 + kg*8]);
#pragma unroll
    for (int n=0;n<2;n++)
      acc[n] = __builtin_amdgcn_mfma_f32_16x16x32_f16(af, bfr[n], acc[n], 0,0,0);
    __syncthreads();
  }
  const int rb = kg*4;
#pragma unroll
  for (int n=0;n<2;n++){
    int col = n*16 + l15;
    float bias = b2[col];
#pragma unroll
    for (int j=0;j<4;j++){
      int g = row0 + wave*16 + rb + j;
      if (g < NN){
        float val = acc[n][j] + bias;
        h0h[(size_t)g*DOUT + col] = (_Float16)val;
        hsh[(size_t)g*DOUT + col] = (_Float16)(nS[g] * val);
      }
    }
  }
}

// ---------- graph prep ----------
__global__ __launch_bounds__(256) void deg_kernel(const int* __restrict__ src, const int* __restrict__ dst,
    int* __restrict__ degO, int* __restrict__ degI){
  int i = blockIdx.x*256 + threadIdx.x;
  if (i < EE){
    atomicAdd(&degO[src[i]], 1);
    atomicAdd(&degI[dst[i]], 1);
  }
}
__global__ __launch_bounds__(256) void norm_kernel(const int* __restrict__ degO, const int* __restrict__ degI,
    float* __restrict__ nS, float* __restrict__ nD){
  int i = blockIdx.x*256 + threadIdx.x;
  if (i < NN){
    int a = degO[i] > 0 ? degO[i] : 1;
    int b = degI[i] > 0 ? degI[i] : 1;
    nS[i] = 1.0f/sqrtf((float)a);
    nD[i] = 1.0f/sqrtf((float)b);
  }
}
__global__ __launch_bounds__(1024) void scan1(const int* __restrict__ degI, int* __restrict__ offs, int* __restrict__ bsum){
  __shared__ int sm[1024];
  int t = threadIdx.x;
  int g = blockIdx.x*1024 + t;
  int v = (g < NN) ? degI[g] : 0;
  sm[t] = v; __syncthreads();
  for (int o=1;o<1024;o<<=1){
    int a = (t>=o)? sm[t-o] : 0;
    __syncthreads();
    sm[t] += a;
    __syncthreads();
  }
  if (g < NN) offs[g] = sm[t] - v;
  if (t == 1023) bsum[blockIdx.x] = sm[t];
}
__global__ __launch_bounds__(128) void scan2(const int* __restrict__ bsum, int* __restrict__ boff, int nb){
  __shared__ int sm[128];
  int t = threadIdx.x;
  int v = (t < nb)? bsum[t] : 0;
  sm[t] = v; __syncthreads();
  for (int o=1;o<128;o<<=1){
    int a = (t>=o)? sm[t-o] : 0;
    __syncthreads();
    sm[t] += a;
    __syncthreads();
  }
  if (t < nb) boff[t] = sm[t] - v;
}
__global__ __launch_bounds__(256) void scan3(int* __restrict__ offs, const int* __restrict__ boff){
  int i = blockIdx.x*256 + threadIdx.x;
  if (i < NN) offs[i] += boff[i >> 10];
}
__global__ __launch_bounds__(256) void scatter_kernel(const int* __restrict__ src, const int* __restrict__ dst,
    const int* __restrict__ offs, int* __restrict__ cursor,
    int* __restrict__ csrc){
  int i = blockIdx.x*256 + threadIdx.x;
  if (i < EE){
    int d = dst[i], s = src[i];
    int pos = offs[d] + atomicAdd(&cursor[d], 1);
    csrc[pos] = s;
  }
}

// ---------- APPNP pull propagation: full 64B rows, 4 slots x 16 lanes, unroll x4 ----------
template<bool LAST>
__global__ __launch_bounds__(256) void prop(
    const unsigned int* __restrict__ hs,   // nS-scaled fp16 rows [NN][16] (uint pairs)
    const unsigned int* __restrict__ h0,   // unscaled fp16 rows [NN][16]
    unsigned int* __restrict__ hs_out,
    float2* __restrict__ out2,             // final f32 out viewed as float2 [NN][16]
    const int* __restrict__ offs, const int* __restrict__ degI,
    const int* __restrict__ csrc,
    const float* __restrict__ nS, const float* __restrict__ nD)
{
  int v = blockIdx.x*4 + (threadIdx.x >> 6);
  if (v >= NN) return;
  int lane = threadIdx.x & 63;
  int slot = lane >> 4;       // 4 edge slots
  int c    = lane & 15;       // uint index within row (feats 2c, 2c+1)
  int beg = offs[v], cnt = degI[v];
  float ax = 0.f, ay = 0.f;

  int i = slot;
  for (; i + 12 < cnt; i += 16){
    int s0 = csrc[beg+i], s1 = csrc[beg+i+4], s2 = csrc[beg+i+8], s3 = csrc[beg+i+12];
    unsigned int p0 = hs[(size_t)s0*16 + c];
    unsigned int p1 = hs[(size_t)s1*16 + c];
    unsigned int p2 = hs[(size_t)s2*16 + c];
    unsigned int p3 = hs[(size_t)s3*16 + c];
    HU u0, u1, u2, u3; u0.u=p0; u1.u=p1; u2.u=p2; u3.u=p3;
    ax += ((float)u0.h[0] + (float)u1.h[0]) + ((float)u2.h[0] + (float)u3.h[0]);
    ay += ((float)u0.h[1] + (float)u1.h[1]) + ((float)u2.h[1] + (float)u3.h[1]);
  }
  for (; i < cnt; i += 4){
    int s0 = csrc[beg+i];
    HU u0; u0.u = hs[(size_t)s0*16 + c];
    ax += (float)u0.h[0];
    ay += (float)u0.h[1];
  }

  ax += __shfl_xor(ax, 16); ay += __shfl_xor(ay, 16);
  ax += __shfl_xor(ax, 32); ay += __shfl_xor(ay, 32);

  if (slot == 0){
    float nd = nD[v];
    HU hp; hp.u = h0[(size_t)v*16 + c];
    float rx = 0.9f*nd*ax + 0.1f*(float)hp.h[0];
    float ry = 0.9f*nd*ay + 0.1f*(float)hp.h[1];
    if (LAST){
      out2[(size_t)v*16 + c] = make_float2(rx, ry);
    } else {
      float ns = nS[v];
      HU o; o.h[0] = (_Float16)(ns*rx); o.h[1] = (_Float16)(ns*ry);
      hs_out[(size_t)v*16 + c] = o.u;
    }
  }
}

extern "C" void kernel_launch(void* const* d_in, const int* in_sizes, int n_in,
                              void* d_out, int out_size, void* d_ws, size_t ws_size,
                              hipStream_t stream)
{
  const float* feats = (const float*)d_in[0];
  const int*   src   = (const int*)d_in[1];
  const int*   dst   = (const int*)d_in[2];
  const float* W1    = (const float*)d_in[3];
  const float* b1    = (const float*)d_in[4];
  const float* W2    = (const float*)d_in[5];
  const float* b2    = (const float*)d_in[6];
  float* out = (float*)d_out;

  char* ws = (char*)d_ws;
  size_t off = 0;
  auto alloc = [&](size_t bytes) -> void* {
    void* p = ws + off;
    off = (off + bytes + 255) & ~(size_t)255;
    return p;
  };
  _Float16* W1T = (_Float16*)alloc((size_t)DIN*DH*2);
  _Float16* W2T = (_Float16*)alloc((size_t)DH*DOUT*2);
  int*   degO   = (int*)  alloc((size_t)NN*4);
  int*   degI   = (int*)  alloc((size_t)NN*4);
  float* nS     = (float*)alloc((size_t)NN*4);
  float* nD     = (float*)alloc((size_t)NN*4);
  int*   offs   = (int*)  alloc((size_t)NN*4);
  int*   cursor = (int*)  alloc((size_t)NN*4);
  int*   bsum   = (int*)  alloc(512);
  int*   boff   = (int*)  alloc(512);
  int*   csrc   = (int*)  alloc((size_t)EE*4);
  _Float16* h0h = (_Float16*)alloc((size_t)NN*DOUT*2);
  _Float16* hs0 = (_Float16*)alloc((size_t)NN*DOUT*2);
  unsigned int* pA = (unsigned int*)alloc((size_t)NN*DOUT*2);
  unsigned int* pB = (unsigned int*)alloc((size_t)NN*DOUT*2);

  hipMemsetAsync(degO,   0, (size_t)NN*4, stream);
  hipMemsetAsync(degI,   0, (size_t)NN*4, stream);
  hipMemsetAsync(cursor, 0, (size_t)NN*4, stream);

  conv_w1<<<(DIN*DH+255)/256, 256, 0, stream>>>(W1, W1T);
  conv_w2<<<(DH*DOUT+255)/256, 256, 0, stream>>>(W2, W2T);

  deg_kernel<<<(EE+255)/256, 256, 0, stream>>>(src, dst, degO, degI);
  norm_kernel<<<(NN+255)/256, 256, 0, stream>>>(degO, degI, nS, nD);

  gemm1<<<dim3(2, (NN+63)/64), 256, 0, stream>>>(feats, W1T, b1, out);
  gemm2<<<(NN+63)/64, 256, 0, stream>>>(out, W2T, b2, nS, h0h, hs0);

  int nb = (NN+1023)/1024;
  scan1<<<nb, 1024, 0, stream>>>(degI, offs, bsum);
  scan2<<<1, 128, 0, stream>>>(bsum, boff, nb);
  scan3<<<(NN+255)/256, 256, 0, stream>>>(offs, boff);
  scatter_kernel<<<(EE+255)/256, 256, 0, stream>>>(src, dst, offs, cursor, csrc);

  float2* out2 = (float2*)(out + (size_t)NN*DH);
  int nbv = (NN + 3) / 4;
  const unsigned int* cur = (const unsigned int*)hs0;
  const unsigned int* h0u = (const unsigned int*)h0h;
  for (int it=0; it<9; ++it){
    unsigned int* nxt = (it&1)? pB : pA;
    prop<false><<<nbv, 256, 0, stream>>>(cur, h0u, nxt, nullptr, offs, degI, csrc, nS, nD);
    cur = nxt;
  }
  prop<true><<<nbv, 256, 0, stream>>>(cur, h0u, nullptr, out2, offs, degI, csrc, nS, nD);
}

// Round 5
// 760.335 us; speedup vs baseline: 1.4195x; 1.0299x over previous
//
#include <hip/hip_runtime.h>

#define NN 100000
#define EE 1600000
#define DIN 512
#define DH 256
#define DOUT 32

typedef _Float16 h16x8 __attribute__((ext_vector_type(8)));
typedef float f32x4 __attribute__((ext_vector_type(4)));

union HU { unsigned int u; _Float16 h[2]; };

// ---------- weight transpose + fp16 convert ----------
__global__ __launch_bounds__(256) void conv_w1(const float* __restrict__ W1, _Float16* __restrict__ W1T){
  int i = blockIdx.x*256 + threadIdx.x;
  if (i < DIN*DH){
    int c = i >> 9, k = i & 511;          // W1T[c][k] = W1[k][c]
    W1T[i] = (_Float16)W1[k*DH + c];
  }
}
__global__ __launch_bounds__(256) void conv_w2(const float* __restrict__ W2, _Float16* __restrict__ W2T){
  int i = blockIdx.x*256 + threadIdx.x;
  if (i < DH*DOUT){
    int c = i >> 8, k = i & 255;          // W2T[c][k] = W2[k][c]
    W2T[i] = (_Float16)W2[k*DOUT + c];
  }
}

// ---------- fused1: LDS-free GEMM1 (h1 = feats @ W1 + b1) co-run with degree+rank ----------
// blocks: 2075 total. Of the first 2048, every (bid&3)==1 is a deg block (512); the
// remaining 1563 are GEMM blocks (BM=64 rows x BN=256 cols, 4 waves x 64x64 tile).
__global__ __launch_bounds__(256) void fused1(
    const float* __restrict__ feats, const _Float16* __restrict__ W1T,
    const float* __restrict__ b1, float* __restrict__ h1,
    const int* __restrict__ src, const int* __restrict__ dst,
    int* __restrict__ degO, int* __restrict__ degI, int* __restrict__ rnk)
{
  const int bid = blockIdx.x;
  const int tid = threadIdx.x;
  if ((bid < 2048) && ((bid & 3) == 1)){
    // ---- degree counting + per-edge rank (insertion slot) ----
    const int db = bid >> 2;                       // 0..511
    for (int i = db*256 + tid; i < EE; i += 512*256){
      atomicAdd(&degO[src[i]], 1);
      rnk[i] = atomicAdd(&degI[dst[i]], 1);
    }
    return;
  }
  const int gid = bid - ((bid < 2048) ? ((bid + 3) >> 2) : 512);
  const int row0 = gid * 64;
  const int lane = tid & 63, wave = tid >> 6;
  const int l15 = lane & 15, kg = lane >> 4;

  f32x4 acc[4][4];
#pragma unroll
  for (int m=0;m<4;m++)
#pragma unroll
    for (int n=0;n<4;n++){ acc[m][n][0]=0.f; acc[m][n][1]=0.f; acc[m][n][2]=0.f; acc[m][n][3]=0.f; }

  const float* aP[4]; bool aok[4];
#pragma unroll
  for (int m=0;m<4;m++){
    int r = row0 + m*16 + l15;
    aok[m] = (r < NN);
    aP[m] = feats + (size_t)r*DIN + kg*8;
  }
  const _Float16* bP[4];
#pragma unroll
  for (int n=0;n<4;n++)
    bP[n] = W1T + (size_t)(wave*64 + n*16 + l15)*DIN + kg*8;

  for (int t=0; t<16; ++t){
    const int k0 = t*32;
    h16x8 bf[4], af[4];
#pragma unroll
    for (int n=0;n<4;n++) bf[n] = *reinterpret_cast<const h16x8*>(bP[n] + k0);
#pragma unroll
    for (int m=0;m<4;m++){
      float4 x = make_float4(0,0,0,0), y = make_float4(0,0,0,0);
      if (aok[m]){
        x = *reinterpret_cast<const float4*>(aP[m] + k0);
        y = *reinterpret_cast<const float4*>(aP[m] + k0 + 4);
      }
      h16x8 v;
      v[0]=(_Float16)x.x; v[1]=(_Float16)x.y; v[2]=(_Float16)x.z; v[3]=(_Float16)x.w;
      v[4]=(_Float16)y.x; v[5]=(_Float16)y.y; v[6]=(_Float16)y.z; v[7]=(_Float16)y.w;
      af[m] = v;
    }
#pragma unroll
    for (int m=0;m<4;m++)
#pragma unroll
      for (int n=0;n<4;n++)
        acc[m][n] = __builtin_amdgcn_mfma_f32_16x16x32_f16(af[m], bf[n], acc[m][n], 0, 0, 0);
  }
  const int rb = kg*4;
#pragma unroll
  for (int n=0;n<4;n++){
    int col = wave*64 + n*16 + l15;
    float bias = b1[col];
#pragma unroll
    for (int m=0;m<4;m++){
#pragma unroll
      for (int j=0;j<4;j++){
        int g = row0 + m*16 + rb + j;
        if (g < NN) h1[(size_t)g*DH + col] = acc[m][n][j] + bias;
      }
    }
  }
}

// ---------- fused2: LDS-free GEMM2 (h0 = relu(h1) @ W2 + b2 -> fp16 + nS-scaled fp16)
// co-run with atomic-free CSR scatter (csrc[offs[d]+rnk[e]] = src[e]).
__global__ __launch_bounds__(256) void fused2(
    const float* __restrict__ h1, const _Float16* __restrict__ W2T,
    const float* __restrict__ b2, const float* __restrict__ nS,
    _Float16* __restrict__ h0h, _Float16* __restrict__ hsh,
    const int* __restrict__ src, const int* __restrict__ dst,
    const int* __restrict__ offs, const int* __restrict__ rnk,
    int* __restrict__ csrc)
{
  const int bid = blockIdx.x;
  const int tid = threadIdx.x;
  if (bid < 1024){
    for (int i = bid*256 + tid; i < EE; i += 1024*256){
      csrc[offs[dst[i]] + rnk[i]] = src[i];
    }
    return;
  }
  const int gid = bid - 1024;
  const int row0 = gid * 256;
  const int lane = tid & 63, wave = tid >> 6;
  const int l15 = lane & 15, kg = lane >> 4;

  f32x4 acc[4][2];
#pragma unroll
  for (int m=0;m<4;m++)
#pragma unroll
    for (int n=0;n<2;n++){ acc[m][n][0]=0.f; acc[m][n][1]=0.f; acc[m][n][2]=0.f; acc[m][n][3]=0.f; }

  const float* aP[4]; bool aok[4];
#pragma unroll
  for (int m=0;m<4;m++){
    int r = row0 + wave*64 + m*16 + l15;
    aok[m] = (r < NN);
    aP[m] = h1 + (size_t)r*DH + kg*8;
  }
  const _Float16* bP[2];
#pragma unroll
  for (int n=0;n<2;n++)
    bP[n] = W2T + (size_t)(n*16 + l15)*DH + kg*8;

  for (int t=0; t<8; ++t){
    const int k0 = t*32;
    h16x8 bf[2], af[4];
#pragma unroll
    for (int n=0;n<2;n++) bf[n] = *reinterpret_cast<const h16x8*>(bP[n] + k0);
#pragma unroll
    for (int m=0;m<4;m++){
      float4 x = make_float4(0,0,0,0), y = make_float4(0,0,0,0);
      if (aok[m]){
        x = *reinterpret_cast<const float4*>(aP[m] + k0);
        y = *reinterpret_cast<const float4*>(aP[m] + k0 + 4);
      }
      h16x8 v;
      v[0]=(_Float16)fmaxf(x.x,0.f); v[1]=(_Float16)fmaxf(x.y,0.f);
      v[2]=(_Float16)fmaxf(x.z,0.f); v[3]=(_Float16)fmaxf(x.w,0.f);
      v[4]=(_Float16)fmaxf(y.x,0.f); v[5]=(_Float16)fmaxf(y.y,0.f);
      v[6]=(_Float16)fmaxf(y.z,0.f); v[7]=(_Float16)fmaxf(y.w,0.f);
      af[m] = v;
    }
#pragma unroll
    for (int m=0;m<4;m++)
#pragma unroll
      for (int n=0;n<2;n++)
        acc[m][n] = __builtin_amdgcn_mfma_f32_16x16x32_f16(af[m], bf[n], acc[m][n], 0, 0, 0);
  }
  const int rb = kg*4;
#pragma unroll
  for (int n=0;n<2;n++){
    int col = n*16 + l15;
    float bias = b2[col];
#pragma unroll
    for (int m=0;m<4;m++){
#pragma unroll
      for (int j=0;j<4;j++){
        int g = row0 + wave*64 + m*16 + rb + j;
        if (g < NN){
          float val = acc[m][n][j] + bias;
          h0h[(size_t)g*DOUT + col] = (_Float16)val;
          hsh[(size_t)g*DOUT + col] = (_Float16)(nS[g] * val);
        }
      }
    }
  }
}

// ---------- graph prep ----------
__global__ __launch_bounds__(256) void norm_kernel(const int* __restrict__ degO, const int* __restrict__ degI,
    float* __restrict__ nS, float* __restrict__ nD){
  int i = blockIdx.x*256 + threadIdx.x;
  if (i < NN){
    int a = degO[i] > 0 ? degO[i] : 1;
    int b = degI[i] > 0 ? degI[i] : 1;
    nS[i] = 1.0f/sqrtf((float)a);
    nD[i] = 1.0f/sqrtf((float)b);
  }
}
__global__ __launch_bounds__(1024) void scan1(const int* __restrict__ degI, int* __restrict__ offs, int* __restrict__ bsum){
  __shared__ int sm[1024];
  int t = threadIdx.x;
  int g = blockIdx.x*1024 + t;
  int v = (g < NN) ? degI[g] : 0;
  sm[t] = v; __syncthreads();
  for (int o=1;o<1024;o<<=1){
    int a = (t>=o)? sm[t-o] : 0;
    __syncthreads();
    sm[t] += a;
    __syncthreads();
  }
  if (g < NN) offs[g] = sm[t] - v;
  if (t == 1023) bsum[blockIdx.x] = sm[t];
}
__global__ __launch_bounds__(128) void scan2(const int* __restrict__ bsum, int* __restrict__ boff, int nb){
  __shared__ int sm[128];
  int t = threadIdx.x;
  int v = (t < nb)? bsum[t] : 0;
  sm[t] = v; __syncthreads();
  for (int o=1;o<128;o<<=1){
    int a = (t>=o)? sm[t-o] : 0;
    __syncthreads();
    sm[t] += a;
    __syncthreads();
  }
  if (t < nb) boff[t] = sm[t] - v;
}
__global__ __launch_bounds__(256) void scan3(int* __restrict__ offs, const int* __restrict__ boff){
  int i = blockIdx.x*256 + threadIdx.x;
  if (i < NN) offs[i] += boff[i >> 10];
}

// ---------- APPNP pull propagation: full 64B rows, 4 slots x 16 lanes, unroll x4 ----------
template<bool LAST>
__global__ __launch_bounds__(256) void prop(
    const unsigned int* __restrict__ hs,   // nS-scaled fp16 rows [NN][16] (uint pairs)
    const unsigned int* __restrict__ h0,   // unscaled fp16 rows [NN][16]
    unsigned int* __restrict__ hs_out,
    float2* __restrict__ out2,             // final f32 out viewed as float2 [NN][16]
    const int* __restrict__ offs, const int* __restrict__ degI,
    const int* __restrict__ csrc,
    const float* __restrict__ nS, const float* __restrict__ nD)
{
  int v = blockIdx.x*4 + (threadIdx.x >> 6);
  if (v >= NN) return;
  int lane = threadIdx.x & 63;
  int slot = lane >> 4;       // 4 edge slots
  int c    = lane & 15;       // uint index within row (feats 2c, 2c+1)
  int beg = offs[v], cnt = degI[v];
  float ax = 0.f, ay = 0.f;

  int i = slot;
  for (; i + 12 < cnt; i += 16){
    int s0 = csrc[beg+i], s1 = csrc[beg+i+4], s2 = csrc[beg+i+8], s3 = csrc[beg+i+12];
    unsigned int p0 = hs[(size_t)s0*16 + c];
    unsigned int p1 = hs[(size_t)s1*16 + c];
    unsigned int p2 = hs[(size_t)s2*16 + c];
    unsigned int p3 = hs[(size_t)s3*16 + c];
    HU u0, u1, u2, u3; u0.u=p0; u1.u=p1; u2.u=p2; u3.u=p3;
    ax += ((float)u0.h[0] + (float)u1.h[0]) + ((float)u2.h[0] + (float)u3.h[0]);
    ay += ((float)u0.h[1] + (float)u1.h[1]) + ((float)u2.h[1] + (float)u3.h[1]);
  }
  for (; i < cnt; i += 4){
    int s0 = csrc[beg+i];
    HU u0; u0.u = hs[(size_t)s0*16 + c];
    ax += (float)u0.h[0];
    ay += (float)u0.h[1];
  }

  ax += __shfl_xor(ax, 16); ay += __shfl_xor(ay, 16);
  ax += __shfl_xor(ax, 32); ay += __shfl_xor(ay, 32);

  if (slot == 0){
    float nd = nD[v];
    HU hp; hp.u = h0[(size_t)v*16 + c];
    float rx = 0.9f*nd*ax + 0.1f*(float)hp.h[0];
    float ry = 0.9f*nd*ay + 0.1f*(float)hp.h[1];
    if (LAST){
      out2[(size_t)v*16 + c] = make_float2(rx, ry);
    } else {
      float ns = nS[v];
      HU o; o.h[0] = (_Float16)(ns*rx); o.h[1] = (_Float16)(ns*ry);
      hs_out[(size_t)v*16 + c] = o.u;
    }
  }
}

extern "C" void kernel_launch(void* const* d_in, const int* in_sizes, int n_in,
                              void* d_out, int out_size, void* d_ws, size_t ws_size,
                              hipStream_t stream)
{
  const float* feats = (const float*)d_in[0];
  const int*   src   = (const int*)d_in[1];
  const int*   dst   = (const int*)d_in[2];
  const float* W1    = (const float*)d_in[3];
  const float* b1    = (const float*)d_in[4];
  const float* W2    = (const float*)d_in[5];
  const float* b2    = (const float*)d_in[6];
  float* out = (float*)d_out;

  char* ws = (char*)d_ws;
  size_t off = 0;
  auto alloc = [&](size_t bytes) -> void* {
    void* p = ws + off;
    off = (off + bytes + 255) & ~(size_t)255;
    return p;
  };
  _Float16* W1T = (_Float16*)alloc((size_t)DIN*DH*2);
  _Float16* W2T = (_Float16*)alloc((size_t)DH*DOUT*2);
  int*   degO   = (int*)  alloc((size_t)NN*4);
  int*   degI   = (int*)  alloc((size_t)NN*4);
  float* nS     = (float*)alloc((size_t)NN*4);
  float* nD     = (float*)alloc((size_t)NN*4);
  int*   offs   = (int*)  alloc((size_t)NN*4);
  int*   bsum   = (int*)  alloc(512);
  int*   boff   = (int*)  alloc(512);
  int*   rnk    = (int*)  alloc((size_t)EE*4);
  int*   csrc   = (int*)  alloc((size_t)EE*4);
  _Float16* h0h = (_Float16*)alloc((size_t)NN*DOUT*2);
  _Float16* hs0 = (_Float16*)alloc((size_t)NN*DOUT*2);
  unsigned int* pA = (unsigned int*)alloc((size_t)NN*DOUT*2);
  unsigned int* pB = (unsigned int*)alloc((size_t)NN*DOUT*2);

  hipMemsetAsync(degO, 0, (size_t)NN*4, stream);
  hipMemsetAsync(degI, 0, (size_t)NN*4, stream);

  conv_w1<<<(DIN*DH+255)/256, 256, 0, stream>>>(W1, W1T);
  conv_w2<<<(DH*DOUT+255)/256, 256, 0, stream>>>(W2, W2T);

  fused1<<<2075, 256, 0, stream>>>(feats, W1T, b1, out, src, dst, degO, degI, rnk);

  norm_kernel<<<(NN+255)/256, 256, 0, stream>>>(degO, degI, nS, nD);
  int nb = (NN+1023)/1024;
  scan1<<<nb, 1024, 0, stream>>>(degI, offs, bsum);
  scan2<<<1, 128, 0, stream>>>(bsum, boff, nb);
  scan3<<<(NN+255)/256, 256, 0, stream>>>(offs, boff);

  fused2<<<1024 + (NN+255)/256, 256, 0, stream>>>(out, W2T, b2, nS, h0h, hs0,
                                                  src, dst, offs, rnk, csrc);

  float2* out2 = (float2*)(out + (size_t)NN*DH);
  int nbv = (NN + 3) / 4;
  const unsigned int* cur = (const unsigned int*)hs0;
  const unsigned int* h0u = (const unsigned int*)h0h;
  for (int it=0; it<9; ++it){
    unsigned int* nxt = (it&1)? pB : pA;
    prop<false><<<nbv, 256, 0, stream>>>(cur, h0u, nxt, nullptr, offs, degI, csrc, nS, nD);
    cur = nxt;
  }
  prop<true><<<nbv, 256, 0, stream>>>(cur, h0u, nullptr, out2, offs, degI, csrc, nS, nD);
}

// Round 6
// 693.625 us; speedup vs baseline: 1.5560x; 1.0962x over previous
//
#include <hip/hip_runtime.h>

#define NN 100000
#define EE 1600000
#define DIN 512
#define DH 256
#define DOUT 32

typedef _Float16 h16x8 __attribute__((ext_vector_type(8)));
typedef _Float16 h16x4 __attribute__((ext_vector_type(4)));
typedef float f32x4 __attribute__((ext_vector_type(4)));

union HU { unsigned int u; _Float16 h[2]; };

// ---------- weight transpose + fp16 convert ----------
__global__ __launch_bounds__(256) void conv_w1(const float* __restrict__ W1, _Float16* __restrict__ W1T){
  int i = blockIdx.x*256 + threadIdx.x;
  if (i < DIN*DH){
    int c = i >> 9, k = i & 511;          // W1T[c][k] = W1[k][c]
    W1T[i] = (_Float16)W1[k*DH + c];
  }
}
__global__ __launch_bounds__(256) void conv_w2(const float* __restrict__ W2, _Float16* __restrict__ W2T){
  int i = blockIdx.x*256 + threadIdx.x;
  if (i < DH*DOUT){
    int c = i >> 8, k = i & 255;          // W2T[c][k] = W2[k][c]
    W2T[i] = (_Float16)W2[k*DOUT + c];
  }
}

// ---------- fused: R3 LDS gemm1 (124us engine) + deg/rank blocks (atomic-pipe, disjoint) ----
// grid: 512 deg blocks, then 3126 gemm blocks (gid: colblk = gid&1, rowblk = gid>>1).
__global__ __launch_bounds__(256) void gemm1_deg(
    const float* __restrict__ feats, const _Float16* __restrict__ W1T,
    const float* __restrict__ b1, float* __restrict__ h1,
    const int* __restrict__ src, const int* __restrict__ dst,
    int* __restrict__ degO, int* __restrict__ degI, int* __restrict__ rnk)
{
  const int bid = blockIdx.x;
  const int tid = threadIdx.x;
  if (bid < 512){
    for (int i = bid*256 + tid; i < EE; i += 512*256){
      atomicAdd(&degO[src[i]], 1);
      rnk[i] = atomicAdd(&degI[dst[i]], 1);
    }
    return;
  }
  const int gid  = bid - 512;
  const int col0 = (gid & 1) * 128;
  const int row0 = (gid >> 1) * 64;

  __shared__ _Float16 At[64][40];
  __shared__ _Float16 Bt[128][40];
  const int lane = tid & 63, wave = tid >> 6;
  const int wr = wave >> 1, wc = wave & 1;
  const int l15 = lane & 15, kg = lane >> 4;
  const int arow = tid >> 2, aseg = (tid & 3) * 8;   // A: 64 rows x 32 k
  const int bcol = tid >> 1, bseg = (tid & 1) * 16;  // B: 128 cols x 32 k
  const bool aok = (row0 + arow) < NN;
  const float* aP = feats + (size_t)(row0+arow)*DIN + aseg;
  const _Float16* bP = W1T + (size_t)(col0+bcol)*DIN + bseg;

  f32x4 acc[2][4];
#pragma unroll
  for (int m=0;m<2;m++)
#pragma unroll
    for (int n=0;n<4;n++){ acc[m][n][0]=0.f; acc[m][n][1]=0.f; acc[m][n][2]=0.f; acc[m][n][3]=0.f; }

  float4 fa0 = make_float4(0,0,0,0), fa1 = make_float4(0,0,0,0);
  h16x8 fb0, fb1;
  if (aok){
    fa0 = *reinterpret_cast<const float4*>(aP);
    fa1 = *reinterpret_cast<const float4*>(aP + 4);
  }
  fb0 = *reinterpret_cast<const h16x8*>(bP);
  fb1 = *reinterpret_cast<const h16x8*>(bP + 8);

  for (int t=0; t<16; ++t){
    {
      h16x4 v0, v1;
      v0[0]=(_Float16)fa0.x; v0[1]=(_Float16)fa0.y; v0[2]=(_Float16)fa0.z; v0[3]=(_Float16)fa0.w;
      v1[0]=(_Float16)fa1.x; v1[1]=(_Float16)fa1.y; v1[2]=(_Float16)fa1.z; v1[3]=(_Float16)fa1.w;
      *reinterpret_cast<h16x4*>(&At[arow][aseg])   = v0;
      *reinterpret_cast<h16x4*>(&At[arow][aseg+4]) = v1;
      *reinterpret_cast<h16x8*>(&Bt[bcol][bseg])   = fb0;
      *reinterpret_cast<h16x8*>(&Bt[bcol][bseg+8]) = fb1;
    }
    __syncthreads();
    if (t < 15){
      int k0 = (t+1)*32;
      if (aok){
        fa0 = *reinterpret_cast<const float4*>(aP + k0);
        fa1 = *reinterpret_cast<const float4*>(aP + k0 + 4);
      }
      fb0 = *reinterpret_cast<const h16x8*>(bP + k0);
      fb1 = *reinterpret_cast<const h16x8*>(bP + k0 + 8);
    }
    h16x8 af[2], bfr[4];
#pragma unroll
    for (int m=0;m<2;m++) af[m]  = *reinterpret_cast<const h16x8*>(&At[wr*32 + m*16 + l15][kg*8]);
#pragma unroll
    for (int n=0;n<4;n++) bfr[n] = *reinterpret_cast<const h16x8*>(&Bt[wc*64 + n*16 + l15][kg*8]);
#pragma unroll
    for (int m=0;m<2;m++)
#pragma unroll
      for (int n=0;n<4;n++)
        acc[m][n] = __builtin_amdgcn_mfma_f32_16x16x32_f16(af[m], bfr[n], acc[m][n], 0, 0, 0);
    __syncthreads();
  }
  const int rb = kg*4;
#pragma unroll
  for (int n=0;n<4;n++){
    int col = col0 + wc*64 + n*16 + l15;
    float bias = b1[col];
#pragma unroll
    for (int m=0;m<2;m++){
#pragma unroll
      for (int j=0;j<4;j++){
        int g = row0 + wr*32 + m*16 + rb + j;
        if (g < NN) h1[(size_t)g*DH + col] = acc[m][n][j] + bias;
      }
    }
  }
}

// ---------- fused2: LDS-free GEMM2 (h0 = relu(h1) @ W2 + b2 -> fp16 + nS-scaled fp16)
// co-run with atomic-free CSR scatter (csrc[offs[d]+rnk[e]] = src[e]).
__global__ __launch_bounds__(256) void fused2(
    const float* __restrict__ h1, const _Float16* __restrict__ W2T,
    const float* __restrict__ b2, const float* __restrict__ nS,
    _Float16* __restrict__ h0h, _Float16* __restrict__ hsh,
    const int* __restrict__ src, const int* __restrict__ dst,
    const int* __restrict__ offs, const int* __restrict__ rnk,
    int* __restrict__ csrc)
{
  const int bid = blockIdx.x;
  const int tid = threadIdx.x;
  if (bid < 1024){
    for (int i = bid*256 + tid; i < EE; i += 1024*256){
      csrc[offs[dst[i]] + rnk[i]] = src[i];
    }
    return;
  }
  const int gid = bid - 1024;
  const int row0 = gid * 256;
  const int lane = tid & 63, wave = tid >> 6;
  const int l15 = lane & 15, kg = lane >> 4;

  f32x4 acc[4][2];
#pragma unroll
  for (int m=0;m<4;m++)
#pragma unroll
    for (int n=0;n<2;n++){ acc[m][n][0]=0.f; acc[m][n][1]=0.f; acc[m][n][2]=0.f; acc[m][n][3]=0.f; }

  const float* aP[4]; bool aok[4];
#pragma unroll
  for (int m=0;m<4;m++){
    int r = row0 + wave*64 + m*16 + l15;
    aok[m] = (r < NN);
    aP[m] = h1 + (size_t)r*DH + kg*8;
  }
  const _Float16* bP[2];
#pragma unroll
  for (int n=0;n<2;n++)
    bP[n] = W2T + (size_t)(n*16 + l15)*DH + kg*8;

  for (int t=0; t<8; ++t){
    const int k0 = t*32;
    h16x8 bf[2], af[4];
#pragma unroll
    for (int n=0;n<2;n++) bf[n] = *reinterpret_cast<const h16x8*>(bP[n] + k0);
#pragma unroll
    for (int m=0;m<4;m++){
      float4 x = make_float4(0,0,0,0), y = make_float4(0,0,0,0);
      if (aok[m]){
        x = *reinterpret_cast<const float4*>(aP[m] + k0);
        y = *reinterpret_cast<const float4*>(aP[m] + k0 + 4);
      }
      h16x8 v;
      v[0]=(_Float16)fmaxf(x.x,0.f); v[1]=(_Float16)fmaxf(x.y,0.f);
      v[2]=(_Float16)fmaxf(x.z,0.f); v[3]=(_Float16)fmaxf(x.w,0.f);
      v[4]=(_Float16)fmaxf(y.x,0.f); v[5]=(_Float16)fmaxf(y.y,0.f);
      v[6]=(_Float16)fmaxf(y.z,0.f); v[7]=(_Float16)fmaxf(y.w,0.f);
      af[m] = v;
    }
#pragma unroll
    for (int m=0;m<4;m++)
#pragma unroll
      for (int n=0;n<2;n++)
        acc[m][n] = __builtin_amdgcn_mfma_f32_16x16x32_f16(af[m], bf[n], acc[m][n], 0, 0, 0);
  }
  const int rb = kg*4;
#pragma unroll
  for (int n=0;n<2;n++){
    int col = n*16 + l15;
    float bias = b2[col];
#pragma unroll
    for (int m=0;m<4;m++){
#pragma unroll
      for (int j=0;j<4;j++){
        int g = row0 + wave*64 + m*16 + rb + j;
        if (g < NN){
          float val = acc[m][n][j] + bias;
          h0h[(size_t)g*DOUT + col] = (_Float16)val;
          hsh[(size_t)g*DOUT + col] = (_Float16)(nS[g] * val);
        }
      }
    }
  }
}

// ---------- graph prep ----------
__global__ __launch_bounds__(256) void norm_kernel(const int* __restrict__ degO, const int* __restrict__ degI,
    float* __restrict__ nS, float* __restrict__ nD){
  int i = blockIdx.x*256 + threadIdx.x;
  if (i < NN){
    int a = degO[i] > 0 ? degO[i] : 1;
    int b = degI[i] > 0 ? degI[i] : 1;
    nS[i] = 1.0f/sqrtf((float)a);
    nD[i] = 1.0f/sqrtf((float)b);
  }
}
__global__ __launch_bounds__(1024) void scan1(const int* __restrict__ degI, int* __restrict__ offs, int* __restrict__ bsum){
  __shared__ int sm[1024];
  int t = threadIdx.x;
  int g = blockIdx.x*1024 + t;
  int v = (g < NN) ? degI[g] : 0;
  sm[t] = v; __syncthreads();
  for (int o=1;o<1024;o<<=1){
    int a = (t>=o)? sm[t-o] : 0;
    __syncthreads();
    sm[t] += a;
    __syncthreads();
  }
  if (g < NN) offs[g] = sm[t] - v;
  if (t == 1023) bsum[blockIdx.x] = sm[t];
}
__global__ __launch_bounds__(128) void scan2(const int* __restrict__ bsum, int* __restrict__ boff, int nb){
  __shared__ int sm[128];
  int t = threadIdx.x;
  int v = (t < nb)? bsum[t] : 0;
  sm[t] = v; __syncthreads();
  for (int o=1;o<128;o<<=1){
    int a = (t>=o)? sm[t-o] : 0;
    __syncthreads();
    sm[t] += a;
    __syncthreads();
  }
  if (t < nb) boff[t] = sm[t] - v;
}
__global__ __launch_bounds__(256) void scan3(int* __restrict__ offs, const int* __restrict__ boff){
  int i = blockIdx.x*256 + threadIdx.x;
  if (i < NN) offs[i] += boff[i >> 10];
}

// ---------- APPNP pull propagation: 8 slots x 8 lanes (uint2), 16 gathers in flight ----------
template<bool LAST>
__global__ __launch_bounds__(256) void prop(
    const uint2* __restrict__ hs,      // nS-scaled fp16 rows [NN][8] (uint2 = 4 feats)
    const uint2* __restrict__ h0,      // unscaled fp16 rows [NN][8]
    uint2* __restrict__ hs_out,
    float4* __restrict__ out4,         // final f32 out viewed as float4 [NN][8]
    const int* __restrict__ offs, const int* __restrict__ degI,
    const int* __restrict__ csrc,
    const float* __restrict__ nS, const float* __restrict__ nD)
{
  int v = blockIdx.x*4 + (threadIdx.x >> 6);
  if (v >= NN) return;
  int lane = threadIdx.x & 63;
  int slot = lane >> 3;       // 8 edge slots
  int c    = lane & 7;        // uint2 index within row (feats 4c..4c+3)
  int beg = offs[v], cnt = degI[v];
  float a0=0.f, a1=0.f, a2=0.f, a3=0.f;

  int i = slot;
  for (; i + 8 < cnt; i += 16){
    int s0 = csrc[beg+i], s1 = csrc[beg+i+8];
    uint2 p0 = hs[(size_t)s0*8 + c];
    uint2 p1 = hs[(size_t)s1*8 + c];
    HU x0,y0,x1,y1; x0.u=p0.x; y0.u=p0.y; x1.u=p1.x; y1.u=p1.y;
    a0 += (float)x0.h[0] + (float)x1.h[0];
    a1 += (float)x0.h[1] + (float)x1.h[1];
    a2 += (float)y0.h[0] + (float)y1.h[0];
    a3 += (float)y0.h[1] + (float)y1.h[1];
  }
  if (i < cnt){
    int s0 = csrc[beg+i];
    uint2 p0 = hs[(size_t)s0*8 + c];
    HU x0,y0; x0.u=p0.x; y0.u=p0.y;
    a0 += (float)x0.h[0];
    a1 += (float)x0.h[1];
    a2 += (float)y0.h[0];
    a3 += (float)y0.h[1];
  }

  a0 += __shfl_xor(a0,8);  a1 += __shfl_xor(a1,8);  a2 += __shfl_xor(a2,8);  a3 += __shfl_xor(a3,8);
  a0 += __shfl_xor(a0,16); a1 += __shfl_xor(a1,16); a2 += __shfl_xor(a2,16); a3 += __shfl_xor(a3,16);
  a0 += __shfl_xor(a0,32); a1 += __shfl_xor(a1,32); a2 += __shfl_xor(a2,32); a3 += __shfl_xor(a3,32);

  if (slot == 0){
    float nd = nD[v];
    uint2 hp = h0[(size_t)v*8 + c];
    HU hx, hy; hx.u = hp.x; hy.u = hp.y;
    float r0 = 0.9f*nd*a0 + 0.1f*(float)hx.h[0];
    float r1 = 0.9f*nd*a1 + 0.1f*(float)hx.h[1];
    float r2 = 0.9f*nd*a2 + 0.1f*(float)hy.h[0];
    float r3 = 0.9f*nd*a3 + 0.1f*(float)hy.h[1];
    if (LAST){
      out4[(size_t)v*8 + c] = make_float4(r0, r1, r2, r3);
    } else {
      float ns = nS[v];
      HU ox, oy;
      ox.h[0]=(_Float16)(ns*r0); ox.h[1]=(_Float16)(ns*r1);
      oy.h[0]=(_Float16)(ns*r2); oy.h[1]=(_Float16)(ns*r3);
      uint2 o; o.x = ox.u; o.y = oy.u;
      hs_out[(size_t)v*8 + c] = o;
    }
  }
}

extern "C" void kernel_launch(void* const* d_in, const int* in_sizes, int n_in,
                              void* d_out, int out_size, void* d_ws, size_t ws_size,
                              hipStream_t stream)
{
  const float* feats = (const float*)d_in[0];
  const int*   src   = (const int*)d_in[1];
  const int*   dst   = (const int*)d_in[2];
  const float* W1    = (const float*)d_in[3];
  const float* b1    = (const float*)d_in[4];
  const float* W2    = (const float*)d_in[5];
  const float* b2    = (const float*)d_in[6];
  float* out = (float*)d_out;

  char* ws = (char*)d_ws;
  size_t off = 0;
  auto alloc = [&](size_t bytes) -> void* {
    void* p = ws + off;
    off = (off + bytes + 255) & ~(size_t)255;
    return p;
  };
  _Float16* W1T = (_Float16*)alloc((size_t)DIN*DH*2);
  _Float16* W2T = (_Float16*)alloc((size_t)DH*DOUT*2);
  int*   degO   = (int*)  alloc((size_t)NN*4);
  int*   degI   = (int*)  alloc((size_t)NN*4);
  float* nS     = (float*)alloc((size_t)NN*4);
  float* nD     = (float*)alloc((size_t)NN*4);
  int*   offs   = (int*)  alloc((size_t)NN*4);
  int*   bsum   = (int*)  alloc(512);
  int*   boff   = (int*)  alloc(512);
  int*   rnk    = (int*)  alloc((size_t)EE*4);
  int*   csrc   = (int*)  alloc((size_t)EE*4);
  _Float16* h0h = (_Float16*)alloc((size_t)NN*DOUT*2);
  _Float16* hs0 = (_Float16*)alloc((size_t)NN*DOUT*2);
  uint2* pA = (uint2*)alloc((size_t)NN*DOUT*2);
  uint2* pB = (uint2*)alloc((size_t)NN*DOUT*2);

  hipMemsetAsync(degO, 0, (size_t)NN*4, stream);
  hipMemsetAsync(degI, 0, (size_t)NN*4, stream);

  conv_w1<<<(DIN*DH+255)/256, 256, 0, stream>>>(W1, W1T);
  conv_w2<<<(DH*DOUT+255)/256, 256, 0, stream>>>(W2, W2T);

  gemm1_deg<<<512 + 2*((NN+63)/64), 256, 0, stream>>>(feats, W1T, b1, out,
                                                      src, dst, degO, degI, rnk);

  norm_kernel<<<(NN+255)/256, 256, 0, stream>>>(degO, degI, nS, nD);
  int nb = (NN+1023)/1024;
  scan1<<<nb, 1024, 0, stream>>>(degI, offs, bsum);
  scan2<<<1, 128, 0, stream>>>(bsum, boff, nb);
  scan3<<<(NN+255)/256, 256, 0, stream>>>(offs, boff);

  fused2<<<1024 + (NN+255)/256, 256, 0, stream>>>(out, W2T, b2, nS, h0h, hs0,
                                                  src, dst, offs, rnk, csrc);

  float4* out4 = (float4*)(out + (size_t)NN*DH);
  int nbv = (NN + 3) / 4;
  const uint2* cur = (const uint2*)hs0;
  const uint2* h0u = (const uint2*)h0h;
  for (int it=0; it<9; ++it){
    uint2* nxt = (it&1)? pB : pA;
    prop<false><<<nbv, 256, 0, stream>>>(cur, h0u, nxt, nullptr, offs, degI, csrc, nS, nD);
    cur = nxt;
  }
  prop<true><<<nbv, 256, 0, stream>>>(cur, h0u, nullptr, out4, offs, degI, csrc, nS, nD);
}